// Round 4
// baseline (1121.931 us; speedup 1.0000x reference)
//
#include <hip/hip_runtime.h>
#include <hip/hip_bf16.h>

// ---------------------------------------------------------------------------
// Treensformer block: x += MHSA(LN1(x)); x += BranchMLP(LN2(x))
// B=64, N_NODES=341, E=512, H=8, hd=64, 4*E=2048, N_LEVELS=4
// Strategy: bf16 MFMA GEMMs (16x16x32), fp32 accumulate/residual.
// R1: MFMA flash attention (was scalar LDS-broadcast-bound, 840us).
// R2: fix compile — vt_lds as native __bf16.
// R3: global_load_lds width=16 async staging in gemm_bf16 (m97 ladder step;
//     517->874 TF on this structure). LDS dest is wave-uniform base +
//     lane*16 — layouts kept contiguous row-major (stride 64B, no pad).
// ---------------------------------------------------------------------------

typedef __attribute__((ext_vector_type(8))) __bf16 bf16x8;
typedef __attribute__((ext_vector_type(4))) float f32x4;
typedef __attribute__((ext_vector_type(4))) unsigned int u32x4;

#define GF_RELU    1
#define GF_OUTBF16 2
#define GF_BIAS2D  4

__constant__ int c_offs[5] = {0, 1, 5, 21, 85};  // node offset per depth

static __device__ __forceinline__ bf16x8 bzero8() {
    u32x4 z = {0u, 0u, 0u, 0u};
    return __builtin_bit_cast(bf16x8, z);
}

// async global->LDS, 16 B per lane; lptr must be wave-uniform (HW adds lane*16)
static __device__ __forceinline__ void async_load16(const void* g, void* l) {
    __builtin_amdgcn_global_load_lds(
        (const __attribute__((address_space(1))) unsigned int*)g,
        (__attribute__((address_space(3))) unsigned int*)l,
        16, 0, 0);
}

// ---------------------------------------------------------------------------
// Weight transpose+convert: out[n*K + k] = bf16(in[k*N + n]); K is pow2.
// ---------------------------------------------------------------------------
__global__ void transpose_bf16_kernel(const float* __restrict__ in,
                                      __hip_bfloat16* __restrict__ out,
                                      int K, int N, int log2K) {
    int idx = blockIdx.x * 256 + threadIdx.x;
    if (idx >= K * N) return;
    int n = idx >> log2K;
    int k = idx & (K - 1);
    out[idx] = __float2bfloat16(in[(size_t)k * N + n]);
}

// ---------------------------------------------------------------------------
// Pack mlp_M (5,5,2048,512) fp32 -> Mcat bf16 per depth d: (2048, 512*(d+1))
// Mcat_d[j, s*512+e] = M[d,s,j,e].  base(d) = d(d+1)/2 * 1048576 elems.
// ---------------------------------------------------------------------------
__global__ void pack_mcat_kernel(const float* __restrict__ M,
                                 __hip_bfloat16* __restrict__ out) {
    int p = blockIdx.y;
    int d = 0;
    while ((d + 1) * (d + 2) / 2 <= p) d++;
    int s = p - d * (d + 1) / 2;
    int idx = blockIdx.x * 256 + threadIdx.x;   // 0 .. 2048*512-1
    int j = idx >> 9;
    int e = idx & 511;
    float v = M[(((size_t)d * 5 + s) * 2048 + j) * 512 + e];
    size_t base = (size_t)(d * (d + 1) / 2) * (2048ull * 512);
    out[base + (size_t)j * (512 * (d + 1)) + s * 512 + e] = __float2bfloat16(v);
}

// ---------------------------------------------------------------------------
// LayerNorm over E=512, one block (256 threads) per token; writes bf16.
// ---------------------------------------------------------------------------
__global__ __launch_bounds__(256) void ln_kernel(const float* __restrict__ x,
                                                 const float* __restrict__ g,
                                                 const float* __restrict__ b,
                                                 __hip_bfloat16* __restrict__ out) {
    int tok = blockIdx.x;
    const float* xr = x + (size_t)tok * 512;
    int t = threadIdx.x;
    float v0 = xr[t], v1 = xr[t + 256];
    float s = v0 + v1;
    float s2 = v0 * v0 + v1 * v1;
    #pragma unroll
    for (int o = 32; o > 0; o >>= 1) {
        s  += __shfl_down(s, o);
        s2 += __shfl_down(s2, o);
    }
    __shared__ float ps[4], ps2[4];
    int w = t >> 6, lane = t & 63;
    if (lane == 0) { ps[w] = s; ps2[w] = s2; }
    __syncthreads();
    if (t == 0) {
        float ts = 0.f, ts2 = 0.f;
        #pragma unroll
        for (int i = 0; i < 4; i++) { ts += ps[i]; ts2 += ps2[i]; }
        ps[0] = ts * (1.f / 512.f);
        ps2[0] = ts2 * (1.f / 512.f);
    }
    __syncthreads();
    float m = ps[0];
    float var = ps2[0] - m * m;
    float r = rsqrtf(var + 1e-5f);
    out[(size_t)tok * 512 + t]       = __float2bfloat16((v0 - m) * r * g[t] + b[t]);
    out[(size_t)tok * 512 + t + 256] = __float2bfloat16((v1 - m) * r * g[t + 256] + b[t + 256]);
}

// ---------------------------------------------------------------------------
// MFMA flash attention (unchanged from R2, 840us -> off top-5).
// ---------------------------------------------------------------------------
#define ATT_STR 72
__global__ __launch_bounds__(256) void attn_mfma_kernel(const __hip_bfloat16* __restrict__ qkv,
                                                        __hip_bfloat16* __restrict__ ctx) {
    __shared__ __bf16 kt_lds[64 * ATT_STR];
    __shared__ __bf16 vt_lds[64 * ATT_STR];
    __shared__ __bf16 pbuf[4 * 48 * ATT_STR];

    const int bh = blockIdx.x;
    const int half = blockIdx.y;
    const int b = bh >> 3, h = bh & 7;
    const int tid = threadIdx.x;
    const int w = tid >> 6, lane = tid & 63;
    const int q = lane >> 4, l16 = lane & 15;
    const int rowbase = half * 192 + w * 48;
    __bf16* pw = pbuf + w * 48 * ATT_STR;

    bf16x8 qf[3][2];
    #pragma unroll
    for (int mi = 0; mi < 3; mi++) {
        int row = rowbase + mi * 16 + l16;
        #pragma unroll
        for (int ks = 0; ks < 2; ks++) {
            if (row < 341)
                qf[mi][ks] = *(const bf16x8*)(qkv + (size_t)(b * 341 + row) * 1536 +
                                              h * 64 + ks * 32 + q * 8);
            else
                qf[mi][ks] = bzero8();
        }
    }

    f32x4 O[3][4];
    float mrun[3][4], lrun[3][4];
    #pragma unroll
    for (int mi = 0; mi < 3; mi++) {
        #pragma unroll
        for (int ni = 0; ni < 4; ni++) { f32x4 z = {0.f,0.f,0.f,0.f}; O[mi][ni] = z; }
        #pragma unroll
        for (int rr = 0; rr < 4; rr++) { mrun[mi][rr] = -1e30f; lrun[mi][rr] = 0.f; }
    }

    for (int kt6 = 0; kt6 < 6; kt6++) {
        const int kbase = kt6 * 64;
        __syncthreads();
        {
            int key = tid >> 2, kg = tid & 3;
            int gk = kbase + key;
            bf16x8 a0 = bzero8(), a1 = bzero8();
            if (gk < 341) {
                const __hip_bfloat16* src =
                    qkv + (size_t)(b * 341 + gk) * 1536 + 512 + h * 64 + kg * 16;
                a0 = *(const bf16x8*)src;
                a1 = *(const bf16x8*)(src + 8);
            }
            *(bf16x8*)(kt_lds + key * ATT_STR + kg * 16)     = a0;
            *(bf16x8*)(kt_lds + key * ATT_STR + kg * 16 + 8) = a1;
        }
        {
            int key = tid & 63, dg = tid >> 6;
            int gk = kbase + key;
            bf16x8 a0 = bzero8(), a1 = bzero8();
            if (gk < 341) {
                const __hip_bfloat16* src =
                    qkv + (size_t)(b * 341 + gk) * 1536 + 1024 + h * 64 + dg * 16;
                a0 = *(const bf16x8*)src;
                a1 = *(const bf16x8*)(src + 8);
            }
            #pragma unroll
            for (int j = 0; j < 8; j++) {
                vt_lds[(dg * 16 + j) * ATT_STR + key]     = a0[j];
                vt_lds[(dg * 16 + 8 + j) * ATT_STR + key] = a1[j];
            }
        }
        __syncthreads();

        f32x4 S[3][4];
        #pragma unroll
        for (int mi = 0; mi < 3; mi++)
            #pragma unroll
            for (int ni = 0; ni < 4; ni++) { f32x4 z = {0.f,0.f,0.f,0.f}; S[mi][ni] = z; }
        #pragma unroll
        for (int ks = 0; ks < 2; ks++) {
            bf16x8 bf_[4];
            #pragma unroll
            for (int ni = 0; ni < 4; ni++)
                bf_[ni] = *(const bf16x8*)(kt_lds + (ni * 16 + l16) * ATT_STR + ks * 32 + q * 8);
            #pragma unroll
            for (int mi = 0; mi < 3; mi++)
                #pragma unroll
                for (int ni = 0; ni < 4; ni++)
                    S[mi][ni] = __builtin_amdgcn_mfma_f32_16x16x32_bf16(qf[mi][ks], bf_[ni],
                                                                        S[mi][ni], 0, 0, 0);
        }

        float cmask[4];
        #pragma unroll
        for (int ni = 0; ni < 4; ni++)
            cmask[ni] = (kbase + ni * 16 + l16 < 341) ? 0.f : -1e30f;

        #pragma unroll
        for (int mi = 0; mi < 3; mi++) {
            #pragma unroll
            for (int rr = 0; rr < 4; rr++) {
                float rmax = -1e30f;
                #pragma unroll
                for (int ni = 0; ni < 4; ni++)
                    rmax = fmaxf(rmax, fmaf(S[mi][ni][rr], 0.125f, cmask[ni]));
                rmax = fmaxf(rmax, __shfl_xor(rmax, 1));
                rmax = fmaxf(rmax, __shfl_xor(rmax, 2));
                rmax = fmaxf(rmax, __shfl_xor(rmax, 4));
                rmax = fmaxf(rmax, __shfl_xor(rmax, 8));
                float mnew = fmaxf(mrun[mi][rr], rmax);
                float alpha = __expf(mrun[mi][rr] - mnew);
                mrun[mi][rr] = mnew;
                float psum = 0.f;
                #pragma unroll
                for (int ni = 0; ni < 4; ni++) {
                    float p = __expf(fmaf(S[mi][ni][rr], 0.125f, cmask[ni]) - mnew);
                    S[mi][ni][rr] = p;
                    psum += p;
                    O[mi][ni][rr] *= alpha;
                }
                psum += __shfl_xor(psum, 1);
                psum += __shfl_xor(psum, 2);
                psum += __shfl_xor(psum, 4);
                psum += __shfl_xor(psum, 8);
                lrun[mi][rr] = lrun[mi][rr] * alpha + psum;
            }
            #pragma unroll
            for (int ni = 0; ni < 4; ni++)
                #pragma unroll
                for (int rr = 0; rr < 4; rr++)
                    pw[(mi * 16 + q * 4 + rr) * ATT_STR + ni * 16 + l16] =
                        (__bf16)S[mi][ni][rr];
        }
        __syncthreads();

        #pragma unroll
        for (int ks = 0; ks < 2; ks++) {
            bf16x8 pf[3], vf[4];
            #pragma unroll
            for (int mi = 0; mi < 3; mi++)
                pf[mi] = *(const bf16x8*)(pw + (mi * 16 + l16) * ATT_STR + ks * 32 + q * 8);
            #pragma unroll
            for (int ni = 0; ni < 4; ni++)
                vf[ni] = *(const bf16x8*)(vt_lds + (ni * 16 + l16) * ATT_STR + ks * 32 + q * 8);
            #pragma unroll
            for (int mi = 0; mi < 3; mi++)
                #pragma unroll
                for (int ni = 0; ni < 4; ni++)
                    O[mi][ni] = __builtin_amdgcn_mfma_f32_16x16x32_bf16(pf[mi], vf[ni],
                                                                        O[mi][ni], 0, 0, 0);
        }
    }

    #pragma unroll
    for (int mi = 0; mi < 3; mi++) {
        #pragma unroll
        for (int rr = 0; rr < 4; rr++) {
            int row = rowbase + mi * 16 + q * 4 + rr;
            if (row >= 341) continue;
            float inv = 1.f / lrun[mi][rr];
            __hip_bfloat16* op = ctx + (size_t)(b * 341 + row) * 512 + h * 64;
            #pragma unroll
            for (int ni = 0; ni < 4; ni++)
                op[ni * 16 + l16] = __float2bfloat16(O[mi][ni][rr] * inv);
        }
    }
}

// ---------------------------------------------------------------------------
// bf16 MFMA GEMM: C(Mrows,N) = A(Mrows,K) @ Bt(N,K)^T [+bias][+resid][relu]
// Tile 128x128xBK32, 256 threads = 4 waves (2x2 of 64x64), 16 mfma/wave/K-step.
// R3: staging via global_load_lds width=16 (async, no VGPR round-trip).
// Wave w, instr j in {0,1}: covers LDS rows [w*32+j*16, +16); lane -> row
// lane>>2, 16B chunk lane&3. A rows clamped to Mrows-1 (no exec-mask lanes;
// garbage confined to C rows the epilogue skips). N, K always mult of 128/32.
// GATHER=true: A row gr -> tree-chain gather; node offset offs[s] computed as
// 0x55555555 & ((1<<2s)-1) (no per-lane constant-mem load in hot loop).
// ---------------------------------------------------------------------------
template <bool GATHER>
__global__ __launch_bounds__(256) void gemm_bf16(
    const __hip_bfloat16* __restrict__ A, const __hip_bfloat16* __restrict__ Bt,
    const float* __restrict__ bias, const float* __restrict__ resid,
    float* __restrict__ Cf, __hip_bfloat16* __restrict__ Cb,
    int Mrows, int N, int K, int flags, int depth) {
    __shared__ __hip_bfloat16 As[128 * 32];
    __shared__ __hip_bfloat16 Bs[128 * 32];
    const int tid = threadIdx.x;
    const int lane = tid & 63;
    const int w = tid >> 6;
    const int srow = lane >> 2;          // 0..15
    const int scol = (lane & 3) << 3;    // bf16 elem offset: 0,8,16,24
    const int wm = (w >> 1) << 6;
    const int wn = (w & 1) << 6;
    const int q = lane >> 4;
    const int l16 = lane & 15;
    const int dsh = GATHER ? (depth << 1) : 0;
    const int bmask = GATHER ? ((1 << dsh) - 1) : 0;

    f32x4 acc[4][4];
    #pragma unroll
    for (int i = 0; i < 4; i++)
        #pragma unroll
        for (int j = 0; j < 4; j++) {
            f32x4 z = {0.f, 0.f, 0.f, 0.f};
            acc[i][j] = z;
        }

    for (int k0 = 0; k0 < K; k0 += 32) {
        __syncthreads();  // previous iteration's fragment reads complete
        #pragma unroll
        for (int j = 0; j < 2; j++) {
            int rloc = w * 32 + j * 16;
            // ---- A tile ----
            int gr = blockIdx.x * 128 + rloc + srow;
            gr = min(gr, Mrows - 1);
            const __hip_bfloat16* ga;
            if (!GATHER) {
                ga = A + (size_t)gr * K + k0 + scol;
            } else {
                int b = gr >> dsh;
                int i = gr & bmask;
                int kk = k0 + scol;
                int s = kk >> 9, e = kk & 511;
                int node = (0x55555555 & ((1 << (s << 1)) - 1)) + (i >> ((depth - s) << 1));
                ga = A + (((size_t)(b * 341 + node)) << 9) + e;
            }
            async_load16(ga, As + rloc * 32);
            // ---- B tile ----
            int gn = blockIdx.y * 128 + rloc + srow;
            async_load16(Bt + (size_t)gn * K + k0 + scol, Bs + rloc * 32);
        }
        __syncthreads();  // drains vmcnt (compiler inserts s_waitcnt before barrier)
        bf16x8 af[4], bfr[4];
        #pragma unroll
        for (int mi = 0; mi < 4; mi++)
            af[mi] = *(const bf16x8*)(As + (wm + mi * 16 + l16) * 32 + q * 8);
        #pragma unroll
        for (int ni = 0; ni < 4; ni++)
            bfr[ni] = *(const bf16x8*)(Bs + (wn + ni * 16 + l16) * 32 + q * 8);
        #pragma unroll
        for (int mi = 0; mi < 4; mi++)
            #pragma unroll
            for (int ni = 0; ni < 4; ni++)
                acc[mi][ni] = __builtin_amdgcn_mfma_f32_16x16x32_bf16(
                    af[mi], bfr[ni], acc[mi][ni], 0, 0, 0);
    }

    #pragma unroll
    for (int mi = 0; mi < 4; mi++) {
        #pragma unroll
        for (int rr = 0; rr < 4; rr++) {
            int grow = blockIdx.x * 128 + wm + mi * 16 + q * 4 + rr;
            if (grow >= Mrows) continue;
            int orow, node = 0;
            if (GATHER) {
                int b = grow >> dsh;
                int i = grow & bmask;
                node = c_offs[depth] + i;
                orow = b * 341 + node;
            } else {
                orow = grow;
            }
            size_t obase = (size_t)orow * N;
            #pragma unroll
            for (int ni = 0; ni < 4; ni++) {
                int col = blockIdx.y * 128 + wn + ni * 16 + l16;
                float v = acc[mi][ni][rr];
                if (bias) v += (flags & GF_BIAS2D) ? bias[(size_t)node * N + col] : bias[col];
                if (resid) v += resid[obase + col];
                if (flags & GF_RELU) v = fmaxf(v, 0.f);
                if (flags & GF_OUTBF16)
                    Cb[obase + col] = __float2bfloat16(v);
                else
                    Cf[obase + col] = v;
            }
        }
    }
}

// ---------------------------------------------------------------------------
extern "C" void kernel_launch(void* const* d_in, const int* in_sizes, int n_in,
                              void* d_out, int out_size, void* d_ws, size_t ws_size,
                              hipStream_t stream) {
    const float* x      = (const float*)d_in[0];
    const float* ln1_g  = (const float*)d_in[1];
    const float* ln1_b  = (const float*)d_in[2];
    const float* w_qkv  = (const float*)d_in[3];
    const float* b_qkv  = (const float*)d_in[4];
    const float* w_proj = (const float*)d_in[5];
    const float* b_proj = (const float*)d_in[6];
    const float* ln2_g  = (const float*)d_in[7];
    const float* ln2_b  = (const float*)d_in[8];
    const float* mlp_M  = (const float*)d_in[9];
    const float* mlp_b1 = (const float*)d_in[10];
    const float* w2     = (const float*)d_in[11];
    const float* b2     = (const float*)d_in[12];
    float* out = (float*)d_out;

    const int M = 64 * 341;  // 21824 rows

    char* ws = (char*)d_ws;
    size_t off = 0;
    auto alloc = [&](size_t bytes) -> char* {
        char* p = ws + off;
        off += (bytes + 255) & ~(size_t)255;
        return p;
    };
    __hip_bfloat16* xn     = (__hip_bfloat16*)alloc((size_t)M * 512 * 2);
    __hip_bfloat16* wqkvT  = (__hip_bfloat16*)alloc(1536ull * 512 * 2);
    __hip_bfloat16* wprojT = (__hip_bfloat16*)alloc(512ull * 512 * 2);
    __hip_bfloat16* w2T    = (__hip_bfloat16*)alloc(512ull * 2048 * 2);
    __hip_bfloat16* mcat   = (__hip_bfloat16*)alloc(15728640ull * 2);
    __hip_bfloat16* qkv    = (__hip_bfloat16*)alloc((size_t)M * 1536 * 2);
    __hip_bfloat16* ctx    = (__hip_bfloat16*)alloc((size_t)M * 512 * 2);
    __hip_bfloat16* hbuf   = (__hip_bfloat16*)alloc((size_t)M * 2048 * 2);
    if (off > ws_size) return;  // workspace too small -> clean validation failure

    // weight prep (bf16, transposed to (N,K))
    transpose_bf16_kernel<<<(512 * 1536 + 255) / 256, 256, 0, stream>>>(w_qkv, wqkvT, 512, 1536, 9);
    transpose_bf16_kernel<<<(512 * 512 + 255) / 256, 256, 0, stream>>>(w_proj, wprojT, 512, 512, 9);
    transpose_bf16_kernel<<<(2048 * 512 + 255) / 256, 256, 0, stream>>>(w2, w2T, 2048, 512, 11);
    pack_mcat_kernel<<<dim3(4096, 15), 256, 0, stream>>>(mlp_M, mcat);

    // attention path
    ln_kernel<<<M, 256, 0, stream>>>(x, ln1_g, ln1_b, xn);
    gemm_bf16<false><<<dim3((M + 127) / 128, 1536 / 128), 256, 0, stream>>>(
        xn, wqkvT, b_qkv, nullptr, nullptr, qkv, M, 1536, 512, GF_OUTBF16, 0);
    attn_mfma_kernel<<<dim3(512, 2), 256, 0, stream>>>(qkv, ctx);
    gemm_bf16<false><<<dim3((M + 127) / 128, 512 / 128), 256, 0, stream>>>(
        ctx, wprojT, b_proj, x, out, nullptr, M, 512, 512, 0, 0);

    // branch MLP path
    ln_kernel<<<M, 256, 0, stream>>>(out, ln2_g, ln2_b, xn);
    for (int d = 0; d <= 4; d++) {
        int Md = 64 << (2 * d);
        size_t base = (size_t)(d * (d + 1) / 2) * (2048ull * 512);
        gemm_bf16<true><<<dim3((Md + 127) / 128, 2048 / 128), 256, 0, stream>>>(
            xn, mcat + base, mlp_b1, nullptr, nullptr, hbuf,
            Md, 2048, 512 * (d + 1), GF_OUTBF16 | GF_RELU | GF_BIAS2D, d);
    }
    gemm_bf16<false><<<dim3((M + 127) / 128, 512 / 128), 256, 0, stream>>>(
        hbuf, w2T, b2, out, out, nullptr, M, 512, 2048, 0, 0);
}

// Round 5
// 860.957 us; speedup vs baseline: 1.3031x; 1.3031x over previous
//
#include <hip/hip_runtime.h>
#include <hip/hip_bf16.h>

// ---------------------------------------------------------------------------
// Treensformer block: x += MHSA(LN1(x)); x += BranchMLP(LN2(x))
// B=64, N_NODES=341, E=512, H=8, hd=64, 4*E=2048, N_LEVELS=4
// Strategy: bf16 MFMA GEMMs (16x16x32), fp32 accumulate/residual.
// R1: MFMA flash attention (was scalar LDS-broadcast-bound, 840us).
// R3: global_load_lds staging -> R4 showed REGRESSION (VALUBusy 19->53%:
//     LDS-dest loads can't hoist above the tile barrier, killed the implicit
//     prefetch). R5: reverted to register staging (R3 = 300us on d=4 GEMM).
// R5: branch-MLP ancestor dedup: group stage-1 by SOURCE depth s —
//     Y_s = x[nodes@s] @ concat_d>=s(M[d,s])^T  (453 matvecs vs 1593,
//     213.8 -> 60.8 GF), then mem-bound combine: h = ReLU(sum_s Y_s + b1).
// ---------------------------------------------------------------------------

typedef __attribute__((ext_vector_type(8))) __bf16 bf16x8;
typedef __attribute__((ext_vector_type(4))) float f32x4;
typedef __attribute__((ext_vector_type(4))) unsigned int u32x4;

#define GF_RELU    1
#define GF_OUTBF16 2

static __device__ __forceinline__ bf16x8 bzero8() {
    u32x4 z = {0u, 0u, 0u, 0u};
    return __builtin_bit_cast(bf16x8, z);
}

// ---------------------------------------------------------------------------
// Weight transpose+convert: out[n*K + k] = bf16(in[k*N + n]); K is pow2.
// ---------------------------------------------------------------------------
__global__ void transpose_bf16_kernel(const float* __restrict__ in,
                                      __hip_bfloat16* __restrict__ out,
                                      int K, int N, int log2K) {
    int idx = blockIdx.x * 256 + threadIdx.x;
    if (idx >= K * N) return;
    int n = idx >> log2K;
    int k = idx & (K - 1);
    out[idx] = __float2bfloat16(in[(size_t)k * N + n]);
}

// ---------------------------------------------------------------------------
// Pack mlp_M (5,5,2048,512) fp32 -> Wcat bf16 grouped by source depth s:
// Wcat_s rows: for d=s..4, M[d,s] (2048x512, natural (j,e) layout) stacked.
// base_s (in 1M=2048*512 units): {0,5,9,12,14}. Pure strided copy.
// grid: (4096, 15); blockIdx.y = (s,d) pair.
// ---------------------------------------------------------------------------
__global__ void pack_wcat_kernel(const float* __restrict__ M,
                                 __hip_bfloat16* __restrict__ out) {
    int p = blockIdx.y;
    int s, d;
    if (p < 5)       { s = 0; d = p; }
    else if (p < 9)  { s = 1; d = p - 4; }
    else if (p < 12) { s = 2; d = p - 7; }
    else if (p < 14) { s = 3; d = p - 9; }
    else             { s = 4; d = 4; }
    const int base_lut[5] = {0, 5, 9, 12, 14};
    size_t idx = (size_t)blockIdx.x * 256 + threadIdx.x;  // 0 .. 2048*512-1
    const size_t MB = 2048ull * 512;
    out[(size_t)base_lut[s] * MB + (size_t)(d - s) * MB + idx] =
        __float2bfloat16(M[((size_t)d * 5 + s) * MB + idx]);
}

// ---------------------------------------------------------------------------
// LayerNorm over E=512, one block (256 threads) per token; writes bf16.
// ---------------------------------------------------------------------------
__global__ __launch_bounds__(256) void ln_kernel(const float* __restrict__ x,
                                                 const float* __restrict__ g,
                                                 const float* __restrict__ b,
                                                 __hip_bfloat16* __restrict__ out) {
    int tok = blockIdx.x;
    const float* xr = x + (size_t)tok * 512;
    int t = threadIdx.x;
    float v0 = xr[t], v1 = xr[t + 256];
    float s = v0 + v1;
    float s2 = v0 * v0 + v1 * v1;
    #pragma unroll
    for (int o = 32; o > 0; o >>= 1) {
        s  += __shfl_down(s, o);
        s2 += __shfl_down(s2, o);
    }
    __shared__ float ps[4], ps2[4];
    int w = t >> 6, lane = t & 63;
    if (lane == 0) { ps[w] = s; ps2[w] = s2; }
    __syncthreads();
    if (t == 0) {
        float ts = 0.f, ts2 = 0.f;
        #pragma unroll
        for (int i = 0; i < 4; i++) { ts += ps[i]; ts2 += ps2[i]; }
        ps[0] = ts * (1.f / 512.f);
        ps2[0] = ts2 * (1.f / 512.f);
    }
    __syncthreads();
    float m = ps[0];
    float var = ps2[0] - m * m;
    float r = rsqrtf(var + 1e-5f);
    out[(size_t)tok * 512 + t]       = __float2bfloat16((v0 - m) * r * g[t] + b[t]);
    out[(size_t)tok * 512 + t + 256] = __float2bfloat16((v1 - m) * r * g[t + 256] + b[t + 256]);
}

// ---------------------------------------------------------------------------
// MFMA flash attention (unchanged from R2).
// ---------------------------------------------------------------------------
#define ATT_STR 72
__global__ __launch_bounds__(256) void attn_mfma_kernel(const __hip_bfloat16* __restrict__ qkv,
                                                        __hip_bfloat16* __restrict__ ctx) {
    __shared__ __bf16 kt_lds[64 * ATT_STR];
    __shared__ __bf16 vt_lds[64 * ATT_STR];
    __shared__ __bf16 pbuf[4 * 48 * ATT_STR];

    const int bh = blockIdx.x;
    const int half = blockIdx.y;
    const int b = bh >> 3, h = bh & 7;
    const int tid = threadIdx.x;
    const int w = tid >> 6, lane = tid & 63;
    const int q = lane >> 4, l16 = lane & 15;
    const int rowbase = half * 192 + w * 48;
    __bf16* pw = pbuf + w * 48 * ATT_STR;

    bf16x8 qf[3][2];
    #pragma unroll
    for (int mi = 0; mi < 3; mi++) {
        int row = rowbase + mi * 16 + l16;
        #pragma unroll
        for (int ks = 0; ks < 2; ks++) {
            if (row < 341)
                qf[mi][ks] = *(const bf16x8*)(qkv + (size_t)(b * 341 + row) * 1536 +
                                              h * 64 + ks * 32 + q * 8);
            else
                qf[mi][ks] = bzero8();
        }
    }

    f32x4 O[3][4];
    float mrun[3][4], lrun[3][4];
    #pragma unroll
    for (int mi = 0; mi < 3; mi++) {
        #pragma unroll
        for (int ni = 0; ni < 4; ni++) { f32x4 z = {0.f,0.f,0.f,0.f}; O[mi][ni] = z; }
        #pragma unroll
        for (int rr = 0; rr < 4; rr++) { mrun[mi][rr] = -1e30f; lrun[mi][rr] = 0.f; }
    }

    for (int kt6 = 0; kt6 < 6; kt6++) {
        const int kbase = kt6 * 64;
        __syncthreads();
        {
            int key = tid >> 2, kg = tid & 3;
            int gk = kbase + key;
            bf16x8 a0 = bzero8(), a1 = bzero8();
            if (gk < 341) {
                const __hip_bfloat16* src =
                    qkv + (size_t)(b * 341 + gk) * 1536 + 512 + h * 64 + kg * 16;
                a0 = *(const bf16x8*)src;
                a1 = *(const bf16x8*)(src + 8);
            }
            *(bf16x8*)(kt_lds + key * ATT_STR + kg * 16)     = a0;
            *(bf16x8*)(kt_lds + key * ATT_STR + kg * 16 + 8) = a1;
        }
        {
            int key = tid & 63, dg = tid >> 6;
            int gk = kbase + key;
            bf16x8 a0 = bzero8(), a1 = bzero8();
            if (gk < 341) {
                const __hip_bfloat16* src =
                    qkv + (size_t)(b * 341 + gk) * 1536 + 1024 + h * 64 + dg * 16;
                a0 = *(const bf16x8*)src;
                a1 = *(const bf16x8*)(src + 8);
            }
            #pragma unroll
            for (int j = 0; j < 8; j++) {
                vt_lds[(dg * 16 + j) * ATT_STR + key]     = a0[j];
                vt_lds[(dg * 16 + 8 + j) * ATT_STR + key] = a1[j];
            }
        }
        __syncthreads();

        f32x4 S[3][4];
        #pragma unroll
        for (int mi = 0; mi < 3; mi++)
            #pragma unroll
            for (int ni = 0; ni < 4; ni++) { f32x4 z = {0.f,0.f,0.f,0.f}; S[mi][ni] = z; }
        #pragma unroll
        for (int ks = 0; ks < 2; ks++) {
            bf16x8 bf_[4];
            #pragma unroll
            for (int ni = 0; ni < 4; ni++)
                bf_[ni] = *(const bf16x8*)(kt_lds + (ni * 16 + l16) * ATT_STR + ks * 32 + q * 8);
            #pragma unroll
            for (int mi = 0; mi < 3; mi++)
                #pragma unroll
                for (int ni = 0; ni < 4; ni++)
                    S[mi][ni] = __builtin_amdgcn_mfma_f32_16x16x32_bf16(qf[mi][ks], bf_[ni],
                                                                        S[mi][ni], 0, 0, 0);
        }

        float cmask[4];
        #pragma unroll
        for (int ni = 0; ni < 4; ni++)
            cmask[ni] = (kbase + ni * 16 + l16 < 341) ? 0.f : -1e30f;

        #pragma unroll
        for (int mi = 0; mi < 3; mi++) {
            #pragma unroll
            for (int rr = 0; rr < 4; rr++) {
                float rmax = -1e30f;
                #pragma unroll
                for (int ni = 0; ni < 4; ni++)
                    rmax = fmaxf(rmax, fmaf(S[mi][ni][rr], 0.125f, cmask[ni]));
                rmax = fmaxf(rmax, __shfl_xor(rmax, 1));
                rmax = fmaxf(rmax, __shfl_xor(rmax, 2));
                rmax = fmaxf(rmax, __shfl_xor(rmax, 4));
                rmax = fmaxf(rmax, __shfl_xor(rmax, 8));
                float mnew = fmaxf(mrun[mi][rr], rmax);
                float alpha = __expf(mrun[mi][rr] - mnew);
                mrun[mi][rr] = mnew;
                float psum = 0.f;
                #pragma unroll
                for (int ni = 0; ni < 4; ni++) {
                    float p = __expf(fmaf(S[mi][ni][rr], 0.125f, cmask[ni]) - mnew);
                    S[mi][ni][rr] = p;
                    psum += p;
                    O[mi][ni][rr] *= alpha;
                }
                psum += __shfl_xor(psum, 1);
                psum += __shfl_xor(psum, 2);
                psum += __shfl_xor(psum, 4);
                psum += __shfl_xor(psum, 8);
                lrun[mi][rr] = lrun[mi][rr] * alpha + psum;
            }
            #pragma unroll
            for (int ni = 0; ni < 4; ni++)
                #pragma unroll
                for (int rr = 0; rr < 4; rr++)
                    pw[(mi * 16 + q * 4 + rr) * ATT_STR + ni * 16 + l16] =
                        (__bf16)S[mi][ni][rr];
        }
        __syncthreads();

        #pragma unroll
        for (int ks = 0; ks < 2; ks++) {
            bf16x8 pf[3], vf[4];
            #pragma unroll
            for (int mi = 0; mi < 3; mi++)
                pf[mi] = *(const bf16x8*)(pw + (mi * 16 + l16) * ATT_STR + ks * 32 + q * 8);
            #pragma unroll
            for (int ni = 0; ni < 4; ni++)
                vf[ni] = *(const bf16x8*)(vt_lds + (ni * 16 + l16) * ATT_STR + ks * 32 + q * 8);
            #pragma unroll
            for (int mi = 0; mi < 3; mi++)
                #pragma unroll
                for (int ni = 0; ni < 4; ni++)
                    O[mi][ni] = __builtin_amdgcn_mfma_f32_16x16x32_bf16(pf[mi], vf[ni],
                                                                        O[mi][ni], 0, 0, 0);
        }
    }

    #pragma unroll
    for (int mi = 0; mi < 3; mi++) {
        #pragma unroll
        for (int rr = 0; rr < 4; rr++) {
            int row = rowbase + mi * 16 + q * 4 + rr;
            if (row >= 341) continue;
            float inv = 1.f / lrun[mi][rr];
            __hip_bfloat16* op = ctx + (size_t)(b * 341 + row) * 512 + h * 64;
            #pragma unroll
            for (int ni = 0; ni < 4; ni++)
                op[ni * 16 + l16] = __float2bfloat16(O[mi][ni][rr] * inv);
        }
    }
}

// ---------------------------------------------------------------------------
// bf16 MFMA GEMM: C(Mrows,N) = A(Mrows,K) @ Bt(N,K)^T [+bias][+resid][relu]
// Tile 128x128xBK32, 256 threads = 4 waves (2x2 of 64x64). R3 register staging
// (global->VGPR loads hoist above the barrier = implicit prefetch; R4 showed
// global_load_lds kills this).
// GATHER=true (self-gather): A row gr -> b = gr>>2s, i = gr & (4^s-1),
// node = offs[s]+i with offs[s] = 0x55555555 & mask; A row = xn[b*341+node].
// Output rows linear (Y_s layout). K=512 in gather mode.
// ---------------------------------------------------------------------------
template <bool GATHER>
__global__ __launch_bounds__(256) void gemm_bf16(
    const __hip_bfloat16* __restrict__ A, const __hip_bfloat16* __restrict__ Bt,
    const float* __restrict__ bias, const float* __restrict__ resid,
    float* __restrict__ Cf, __hip_bfloat16* __restrict__ Cb,
    int Mrows, int N, int K, int flags, int depth) {
    __shared__ __hip_bfloat16 As[128 * 32];
    __shared__ __hip_bfloat16 Bs[128 * 32];
    const int tid = threadIdx.x;
    const int r = tid >> 1;            // staging row 0..127
    const int kh = (tid & 1) << 4;     // 0 / 16
    const int gr = blockIdx.x * 128 + r;
    const int gn = blockIdx.y * 128 + r;
    const int lane = tid & 63;
    const int w = tid >> 6;
    const int wm = (w >> 1) << 6;
    const int wn = (w & 1) << 6;
    const int q = lane >> 4;
    const int l16 = lane & 15;

    size_t abase;
    if (GATHER) {
        const int dsh = depth << 1;
        const int bmask = (1 << dsh) - 1;
        int b = gr >> dsh;
        int i = gr & bmask;
        int node = (0x55555555 & bmask) + i;   // offs[depth] + i
        abase = ((size_t)(b * 341 + node)) << 9;
    } else {
        abase = (size_t)gr * K;
    }

    f32x4 acc[4][4];
    #pragma unroll
    for (int i = 0; i < 4; i++)
        #pragma unroll
        for (int j = 0; j < 4; j++) {
            f32x4 z = {0.f, 0.f, 0.f, 0.f};
            acc[i][j] = z;
        }

    for (int k0 = 0; k0 < K; k0 += 32) {
        bf16x8 va0 = bzero8(), va1 = bzero8(), vb0, vb1;
        if (gr < Mrows) {
            const bf16x8* p = (const bf16x8*)(A + abase + k0 + kh);
            va0 = p[0];
            va1 = p[1];
        }
        {
            const bf16x8* p = (const bf16x8*)(Bt + (size_t)gn * K + k0 + kh);
            vb0 = p[0];
            vb1 = p[1];
        }
        __syncthreads();  // previous iteration's fragment reads complete
        *(bf16x8*)(As + r * 32 + kh)     = va0;
        *(bf16x8*)(As + r * 32 + kh + 8) = va1;
        *(bf16x8*)(Bs + r * 32 + kh)     = vb0;
        *(bf16x8*)(Bs + r * 32 + kh + 8) = vb1;
        __syncthreads();
        bf16x8 af[4], bfr[4];
        #pragma unroll
        for (int mi = 0; mi < 4; mi++)
            af[mi] = *(const bf16x8*)(As + (wm + mi * 16 + l16) * 32 + q * 8);
        #pragma unroll
        for (int ni = 0; ni < 4; ni++)
            bfr[ni] = *(const bf16x8*)(Bs + (wn + ni * 16 + l16) * 32 + q * 8);
        #pragma unroll
        for (int mi = 0; mi < 4; mi++)
            #pragma unroll
            for (int ni = 0; ni < 4; ni++)
                acc[mi][ni] = __builtin_amdgcn_mfma_f32_16x16x32_bf16(
                    af[mi], bfr[ni], acc[mi][ni], 0, 0, 0);
    }

    #pragma unroll
    for (int mi = 0; mi < 4; mi++) {
        #pragma unroll
        for (int rr = 0; rr < 4; rr++) {
            int grow = blockIdx.x * 128 + wm + mi * 16 + q * 4 + rr;
            if (grow >= Mrows) continue;
            size_t obase = (size_t)grow * N;
            #pragma unroll
            for (int ni = 0; ni < 4; ni++) {
                int col = blockIdx.y * 128 + wn + ni * 16 + l16;
                float v = acc[mi][ni][rr];
                if (bias) v += bias[col];
                if (resid) v += resid[obase + col];
                if (flags & GF_RELU) v = fmaxf(v, 0.f);
                if (flags & GF_OUTBF16)
                    Cb[obase + col] = __float2bfloat16(v);
                else
                    Cf[obase + col] = v;
            }
        }
    }
}

// ---------------------------------------------------------------------------
// Combine: h[b,node@d,:] = ReLU( sum_{s<=d} Y_s[b*4^s + anc_s, (d-s) block] + b1[node] )
// One block per (b,node) row; thread t handles 8 cols (j = t*8). Mem-bound.
// Y_s row width = (5-s)*2048; yoff = cumulative elem offsets.
// ---------------------------------------------------------------------------
__global__ __launch_bounds__(256) void combine_kernel(const __hip_bfloat16* __restrict__ Y,
                                                      const float* __restrict__ b1,
                                                      __hip_bfloat16* __restrict__ h) {
    const size_t yoff[5] = {0, 655360, 2752512, 9043968, 25821184};
    int row = blockIdx.x;
    int b = row / 341;
    int node = row - b * 341;
    int d = (node >= 85) ? 4 : (node >= 21) ? 3 : (node >= 5) ? 2 : (node >= 1) ? 1 : 0;
    int i = node - (0x55555555 & ((1 << (d << 1)) - 1));
    int j = threadIdx.x << 3;

    float acc[8];
    const float* bp = b1 + (size_t)node * 2048 + j;
    f32x4 b0 = *(const f32x4*)bp;
    f32x4 b4 = *(const f32x4*)(bp + 4);
    #pragma unroll
    for (int u = 0; u < 4; u++) { acc[u] = b0[u]; acc[u + 4] = b4[u]; }

    #pragma unroll
    for (int s = 0; s < 5; s++) {
        if (s <= d) {
            int a = i >> ((d - s) << 1);
            int width = (5 - s) << 11;
            const bf16x8 v = *(const bf16x8*)(Y + yoff[s] +
                (size_t)((b << (s << 1)) + a) * width + ((d - s) << 11) + j);
            #pragma unroll
            for (int u = 0; u < 8; u++) acc[u] += (float)v[u];
        }
    }
    bf16x8 o;
    #pragma unroll
    for (int u = 0; u < 8; u++) o[u] = (__bf16)fmaxf(acc[u], 0.f);
    *(bf16x8*)(h + (size_t)row * 2048 + j) = o;
}

// ---------------------------------------------------------------------------
extern "C" void kernel_launch(void* const* d_in, const int* in_sizes, int n_in,
                              void* d_out, int out_size, void* d_ws, size_t ws_size,
                              hipStream_t stream) {
    const float* x      = (const float*)d_in[0];
    const float* ln1_g  = (const float*)d_in[1];
    const float* ln1_b  = (const float*)d_in[2];
    const float* w_qkv  = (const float*)d_in[3];
    const float* b_qkv  = (const float*)d_in[4];
    const float* w_proj = (const float*)d_in[5];
    const float* b_proj = (const float*)d_in[6];
    const float* ln2_g  = (const float*)d_in[7];
    const float* ln2_b  = (const float*)d_in[8];
    const float* mlp_M  = (const float*)d_in[9];
    const float* mlp_b1 = (const float*)d_in[10];
    const float* w2     = (const float*)d_in[11];
    const float* b2     = (const float*)d_in[12];
    float* out = (float*)d_out;

    const int M = 64 * 341;  // 21824 rows

    char* ws = (char*)d_ws;
    size_t off = 0;
    auto alloc = [&](size_t bytes) -> char* {
        char* p = ws + off;
        off += (bytes + 255) & ~(size_t)255;
        return p;
    };
    __hip_bfloat16* xn     = (__hip_bfloat16*)alloc((size_t)M * 512 * 2);
    __hip_bfloat16* wqkvT  = (__hip_bfloat16*)alloc(1536ull * 512 * 2);
    __hip_bfloat16* wprojT = (__hip_bfloat16*)alloc(512ull * 512 * 2);
    __hip_bfloat16* w2T    = (__hip_bfloat16*)alloc(512ull * 2048 * 2);
    __hip_bfloat16* wcat   = (__hip_bfloat16*)alloc(15ull * 2048 * 512 * 2);
    __hip_bfloat16* hbuf   = (__hip_bfloat16*)alloc((size_t)M * 2048 * 2);
    // shared region: qkv+ctx (attention phase) overlaid by Y (branch phase)
    const size_t qkv_bytes = (size_t)M * 1536 * 2;            // 67,043,328
    const size_t y_bytes   = 59375616ull * 2;                 // 118,751,232
    char* shared = alloc(y_bytes);                            // >= qkv+ctx
    __hip_bfloat16* qkv = (__hip_bfloat16*)shared;
    __hip_bfloat16* ctx = (__hip_bfloat16*)(shared + qkv_bytes);
    __hip_bfloat16* Y   = (__hip_bfloat16*)shared;
    if (off > ws_size) return;  // workspace too small -> clean validation failure

    // weight prep
    transpose_bf16_kernel<<<(512 * 1536 + 255) / 256, 256, 0, stream>>>(w_qkv, wqkvT, 512, 1536, 9);
    transpose_bf16_kernel<<<(512 * 512 + 255) / 256, 256, 0, stream>>>(w_proj, wprojT, 512, 512, 9);
    transpose_bf16_kernel<<<(2048 * 512 + 255) / 256, 256, 0, stream>>>(w2, w2T, 2048, 512, 11);
    pack_wcat_kernel<<<dim3(4096, 15), 256, 0, stream>>>(mlp_M, wcat);

    // attention path
    ln_kernel<<<M, 256, 0, stream>>>(x, ln1_g, ln1_b, xn);
    gemm_bf16<false><<<dim3((M + 127) / 128, 1536 / 128), 256, 0, stream>>>(
        xn, wqkvT, b_qkv, nullptr, nullptr, qkv, M, 1536, 512, GF_OUTBF16, 0);
    attn_mfma_kernel<<<dim3(512, 2), 256, 0, stream>>>(qkv, ctx);
    gemm_bf16<false><<<dim3((M + 127) / 128, 512 / 128), 256, 0, stream>>>(
        ctx, wprojT, b_proj, x, out, nullptr, M, 512, 512, 0, 0);

    // branch MLP path (dedup by source depth s)
    ln_kernel<<<M, 256, 0, stream>>>(out, ln2_g, ln2_b, xn);
    const size_t yoff[5]     = {0, 655360, 2752512, 9043968, 25821184};
    const size_t wcat_off[5] = {0, 5, 9, 12, 14};  // in 2048*512 units
    for (int s = 0; s <= 4; s++) {
        int rows = 64 << (2 * s);
        int Ns = (5 - s) * 2048;
        gemm_bf16<true><<<dim3((rows + 127) / 128, Ns / 128), 256, 0, stream>>>(
            xn, wcat + wcat_off[s] * (2048ull * 512), nullptr, nullptr, nullptr,
            Y + yoff[s], rows, Ns, 512, GF_OUTBF16, s);
    }
    combine_kernel<<<M, 256, 0, stream>>>(Y, mlp_b1, hbuf);
    gemm_bf16<false><<<dim3((M + 127) / 128, 512 / 128), 256, 0, stream>>>(
        hbuf, w2T, b2, out, out, nullptr, M, 512, 2048, 0, 0);
}